// Round 11
// baseline (677.441 us; speedup 1.0000x reference)
//
#include <hip/hip_runtime.h>
#include <hip/hip_bf16.h>

// ---------------------------------------------------------------------------
// HybridFFN: y = 0.5*gelu_mlp(x) + 0.5*top1_moe_swiglu(x), aux load-balance loss
// Ups (K=1024): 256x256 8-phase (T2+T3/T4+T5).
// Down: TWO K=4096 halves as separate blocks in one launch (1024 active = 4/CU,
//       the m103 regime), R6's proven 128x128 BK=32 2-phase body, XCD decode.
//       Dense half -> yA bf16 linear (aliases dead xg); moe half -> y direct.
//       Combine pass: y[rev[r]] += 0.5*(yA[r] + b2).  No atomics, no in-kernel RMW.
// Memory plan (~206 MB): hd ALIASES ew13t; yA ALIASES xg.
// ---------------------------------------------------------------------------

static constexpr int MT = 8192;   // B*S tokens
static constexpr int DD = 1024;   // model dim
static constexpr int DI = 4096;   // inner dim

typedef float f32x4 __attribute__((ext_vector_type(4)));
typedef __bf16 bf16x8 __attribute__((ext_vector_type(8)));
typedef unsigned short u16;

__device__ __forceinline__ u16 f2bf(float f) {
    union { __hip_bfloat16 b; u16 u; } v;
    v.b = __float2bfloat16(f);
    return v.u;
}
__device__ __forceinline__ float bf2f(u16 u) {
    union { float f; unsigned i; } v;
    v.i = ((unsigned)u) << 16;
    return v.f;
}

__device__ __forceinline__ void gload_lds16(const void* g, void* l) {
    __builtin_amdgcn_global_load_lds(
        (const __attribute__((address_space(1))) void*)g,
        (__attribute__((address_space(3))) void*)l, 16, 0, 0);
}

__device__ __forceinline__ float gelu_f(float v) {
    return 0.5f * v * (1.0f + erff(v * 0.70710678118654752f));
}
__device__ __forceinline__ float silu_f(float v) {
    return v / (1.0f + expf(-v));
}

#define FENCE() asm volatile("" ::: "memory")
#define BARRIER() do { FENCE(); __builtin_amdgcn_s_barrier(); FENCE(); } while (0)
#define WAIT_LGKM0() asm volatile("s_waitcnt lgkmcnt(0)" ::: "memory")

// ---------------------------------------------------------------------------
// Transpose tile helper: src f32 [K][N] -> dst bf16 [N'][K], 64x64 tile.
// pack=1 remaps dst row n -> (n/32)*64 + (n%32) + packOff  (SwiGLU col-pairing)
// ---------------------------------------------------------------------------
__device__ __forceinline__ void transpose_tile(
    const float* __restrict__ s, u16* __restrict__ d, int K, int N,
    int pack, int packOff) {
    __shared__ u16 t[64][72];
    int n0 = blockIdx.x * 64, k0 = blockIdx.y * 64;
    int tid = threadIdx.x;
    int c = tid & 15;
    int r = tid >> 4;
#pragma unroll
    for (int p = 0; p < 4; ++p) {
        int k = r + p * 16;
        float4 v = *(const float4*)(s + (size_t)(k0 + k) * N + n0 + c * 4);
        t[c * 4 + 0][k] = f2bf(v.x);
        t[c * 4 + 1][k] = f2bf(v.y);
        t[c * 4 + 2][k] = f2bf(v.z);
        t[c * 4 + 3][k] = f2bf(v.w);
    }
    __syncthreads();
    int n = tid >> 2, kc = (tid & 3) * 16;
    const uint4* p0 = (const uint4*)&t[n][kc];
    uint4 a = p0[0], b = p0[1];
    int gn = n0 + n;
    int dr = pack ? ((gn >> 5) * 64 + (gn & 31) + packOff) : gn;
    uint4* o = (uint4*)(d + (size_t)dr * K + k0 + kc);
    o[0] = a; o[1] = b;
}

// up-weights: z=0 -> W1->W1t; z in 1..4 -> ew1[z-1]->ew13t(packOff 0);
//             z in 5..8 -> ew3[z-5]->ew13t(packOff 32).   [K=DD, N=DI]
__global__ void __launch_bounds__(256) transpose_up(
    const float* __restrict__ W1, const float* __restrict__ ew1,
    const float* __restrict__ ew3, u16* __restrict__ W1t,
    u16* __restrict__ ew13t) {
    int z = blockIdx.z;
    if (z == 0) {
        transpose_tile(W1, W1t, DD, DI, 0, 0);
    } else if (z <= 4) {
        transpose_tile(ew1 + (size_t)(z - 1) * DD * DI,
                       ew13t + (size_t)(z - 1) * 2 * DD * DI, DD, DI, 1, 0);
    } else {
        transpose_tile(ew3 + (size_t)(z - 5) * DD * DI,
                       ew13t + (size_t)(z - 5) * 2 * DD * DI, DD, DI, 1, 32);
    }
}

// down-weights: z=0 -> W2->W2t; z in 1..4 -> ew2[z-1]->ew2t.   [K=DI, N=DD]
__global__ void __launch_bounds__(256) transpose_dn(
    const float* __restrict__ W2, const float* __restrict__ ew2,
    u16* __restrict__ W2t, u16* __restrict__ ew2t) {
    int z = blockIdx.z;
    if (z == 0) {
        transpose_tile(W2, W2t, DI, DD, 0, 0);
    } else {
        transpose_tile(ew2 + (size_t)(z - 1) * DI * DD,
                       ew2t + (size_t)(z - 1) * DI * DD, DI, DD, 0, 0);
    }
}

// ---------------------------------------------------------------------------
// Gating: one wave per token; fp64 logits, softmax, argmax. No atomics.
// ---------------------------------------------------------------------------
__global__ void __launch_bounds__(256) gate_kernel(
    const float* __restrict__ x, const float* __restrict__ Wg,
    float* __restrict__ psum_blk, int* __restrict__ expertA) {
    int w = threadIdx.x >> 6, l = threadIdx.x & 63;
    int t = blockIdx.x * 4 + w;
    const float* xr = x + (size_t)t * DD;
    double a0 = 0, a1 = 0, a2 = 0, a3 = 0;
#pragma unroll
    for (int i = 0; i < 4; ++i) {
        int k = i * 256 + l * 4;
        float4 xv = *(const float4*)(xr + k);
        float4 w0 = *(const float4*)(Wg + (size_t)(k + 0) * 4);
        float4 w1 = *(const float4*)(Wg + (size_t)(k + 1) * 4);
        float4 w2 = *(const float4*)(Wg + (size_t)(k + 2) * 4);
        float4 w3 = *(const float4*)(Wg + (size_t)(k + 3) * 4);
        a0 += (double)xv.x * w0.x + (double)xv.y * w1.x + (double)xv.z * w2.x + (double)xv.w * w3.x;
        a1 += (double)xv.x * w0.y + (double)xv.y * w1.y + (double)xv.z * w2.y + (double)xv.w * w3.y;
        a2 += (double)xv.x * w0.z + (double)xv.y * w1.z + (double)xv.z * w2.z + (double)xv.w * w3.z;
        a3 += (double)xv.x * w0.w + (double)xv.y * w1.w + (double)xv.z * w2.w + (double)xv.w * w3.w;
    }
#pragma unroll
    for (int o = 32; o; o >>= 1) {
        a0 += __shfl_down(a0, o); a1 += __shfl_down(a1, o);
        a2 += __shfl_down(a2, o); a3 += __shfl_down(a3, o);
    }
    __shared__ float wps[4][4];
    if (l == 0) {
        double lg[4] = {a0, a1, a2, a3};
        int best = 0;
#pragma unroll
        for (int e = 1; e < 4; ++e) if (lg[e] > lg[best]) best = e;
        double m = lg[best], s = 0, p[4];
#pragma unroll
        for (int e = 0; e < 4; ++e) { p[e] = exp(lg[e] - m); s += p[e]; }
#pragma unroll
        for (int e = 0; e < 4; ++e) wps[w][e] = (float)(p[e] / s);
        expertA[t] = best;
    }
    __syncthreads();
    if (threadIdx.x < 4)
        psum_blk[blockIdx.x * 4 + threadIdx.x] =
            wps[0][threadIdx.x] + wps[1][threadIdx.x] + wps[2][threadIdx.x] + wps[3][threadIdx.x];
}

// ---------------------------------------------------------------------------
// Single-block stable compaction + offsets + aux loss.
// ---------------------------------------------------------------------------
__global__ void __launch_bounds__(1024) build_lists(
    const int* __restrict__ expertA, const float* __restrict__ psum_blk,
    int* __restrict__ dstArr, int* __restrict__ rev,
    int* __restrict__ offsets, float* __restrict__ auxOut) {
    __shared__ int sc[4][1024];
    __shared__ float fs[1024];
    __shared__ float psum_s[4];
    __shared__ int tot_s[4], off_s[4];
    int tid = threadIdx.x;
    int le[8]; int c[4] = {0, 0, 0, 0};
#pragma unroll
    for (int i = 0; i < 8; ++i) { int e = expertA[tid * 8 + i]; le[i] = e; c[e]++; }
#pragma unroll
    for (int e = 0; e < 4; ++e) sc[e][tid] = c[e];
    __syncthreads();
    for (int o = 1; o < 1024; o <<= 1) {
        int v[4];
#pragma unroll
        for (int e = 0; e < 4; ++e) v[e] = (tid >= o) ? sc[e][tid - o] : 0;
        __syncthreads();
#pragma unroll
        for (int e = 0; e < 4; ++e) if (tid >= o) sc[e][tid] += v[e];
        __syncthreads();
    }
    if (tid == 0) {
        int o = 0;
#pragma unroll
        for (int e = 0; e < 4; ++e) {
            tot_s[e] = sc[e][1023]; off_s[e] = o; offsets[e] = o; o += tot_s[e];
        }
        offsets[4] = o;
    }
    __syncthreads();
    int base[4];
#pragma unroll
    for (int e = 0; e < 4; ++e) base[e] = off_s[e] + sc[e][tid] - c[e];
#pragma unroll
    for (int i = 0; i < 8; ++i) {
        int e = le[i]; int d = base[e]++; int t = tid * 8 + i;
        dstArr[t] = d; rev[d] = t;
    }
    float ps[4];
#pragma unroll
    for (int e = 0; e < 4; ++e)
        ps[e] = psum_blk[(2 * tid) * 4 + e] + psum_blk[(2 * tid + 1) * 4 + e];
    for (int e = 0; e < 4; ++e) {
        fs[tid] = ps[e]; __syncthreads();
        for (int o = 512; o; o >>= 1) { if (tid < o) fs[tid] += fs[tid + o]; __syncthreads(); }
        if (tid == 0) psum_s[e] = fs[0];
        __syncthreads();
    }
    if (tid == 0) {
        float a = 0;
#pragma unroll
        for (int e = 0; e < 4; ++e)
            a += ((float)tot_s[e] * (1.f / 8192.f)) * (psum_s[e] * (1.f / 8192.f));
        auxOut[0] = 4.f * a;
    }
}

// ---------------------------------------------------------------------------
// Gather: bf16 rows into xg (expert-sorted order only).
// ---------------------------------------------------------------------------
__global__ void __launch_bounds__(256) gather_kernel(
    const float* __restrict__ x, const int* __restrict__ dstArr,
    u16* __restrict__ xg) {
    int w = threadIdx.x >> 6, l = threadIdx.x & 63;
    int t = blockIdx.x * 4 + w;
    int dst = dstArr[t];
    const float* xr = x + (size_t)t * DD;
#pragma unroll
    for (int i = 0; i < 4; ++i) {
        int k = i * 256 + l * 4;
        float4 v = *(const float4*)(xr + k);
        ushort4 u;
        u.x = f2bf(v.x); u.y = f2bf(v.y); u.z = f2bf(v.z); u.w = f2bf(v.w);
        *(ushort4*)(xg + (size_t)dst * DD + k) = u;
    }
}

// ---------------------------------------------------------------------------
// Up-GEMMs: 256-row 8-phase MFMA GEMM (BM=256, BK=64, 8 waves 2x4, dbuf LDS,
// st_16x32 swizzle, counted vmcnt, setprio).
// MODE 0 (NF=4): h = gelu(A@W + b)            -> bf16 (rows = sorted tokens)
// MODE 2 (NF=4): h = silu(A@W1)*(A@W3)        -> bf16, ragged, packed B cols
// ---------------------------------------------------------------------------
template <int MODE, int NF>
__global__ void __launch_bounds__(512, 2) gemm8(
    const u16* __restrict__ A, const u16* __restrict__ Bw,
    const float* __restrict__ bias,
    u16* __restrict__ outB, float* __restrict__ outF,
    const int* __restrict__ offsets, const int* __restrict__ rev,
    int N, int K) {
    constexpr int BN   = NF * 64;
    constexpr int WCW  = NF * 16;
    constexpr int AELT = 2 * 256 * 32;
    constexpr int BUFE = AELT + 2 * BN * 32;
    constexpr int NIB  = NF / 2;
    __shared__ u16 lds[2 * BUFE];

    const int tid = threadIdx.x;
    const int w = tid >> 6, l = tid & 63;
    const int lr = l & 15, lg = l >> 4;
    const int wr = w >> 2, wc = w & 3;

    int rowBase, rowsValid = 256;
    const u16* Bp = Bw;
    if constexpr (MODE >= 2) {
        int e = blockIdx.z;
        int off = offsets[e], cnt = offsets[e + 1] - off;
        if ((int)blockIdx.y * 256 >= cnt) return;
        rowBase = off + blockIdx.y * 256;
        rowsValid = cnt - (int)blockIdx.y * 256;
        if (rowsValid > 256) rowsValid = 256;
        Bp = Bw + (size_t)e * ((size_t)2 * DD * DI);
    } else {
        rowBase = blockIdx.y * 256;
    }
    const int colBase = blockIdx.x * BN;
    const int NT = K >> 6;

    auto stageA = [&](int kt, int b, int ks) {
        const int kk = (kt << 6) + (ks << 5);
#pragma unroll
        for (int i = 0; i < 2; ++i) {
            int o = ((w << 1) + i) * 512 + (l << 3);
            int o2 = o ^ (((o >> 8) & 1) << 4);
            gload_lds16(A + (size_t)(rowBase + (o2 >> 5)) * K + kk + (o2 & 31),
                        &lds[b * BUFE + ks * 8192 + ((w << 1) + i) * 512]);
        }
    };
    auto stageB = [&](int kt, int b, int ks) {
        const int kk = (kt << 6) + (ks << 5);
#pragma unroll
        for (int i = 0; i < NIB; ++i) {
            int o = (w * NIB + i) * 512 + (l << 3);
            int o2 = o ^ (((o >> 8) & 1) << 4);
            gload_lds16(Bp + (size_t)(colBase + (o2 >> 5)) * K + kk + (o2 & 31),
                        &lds[b * BUFE + AELT + ks * (BN * 32) + (w * NIB + i) * 512]);
        }
    };

#define WAIT_VMB() do { \
    if constexpr (NF == 4) asm volatile("s_waitcnt vmcnt(4)" ::: "memory"); \
    else                   asm volatile("s_waitcnt vmcnt(3)" ::: "memory"); \
} while (0)

#define READBF(b_, ks_) do { \
    _Pragma("unroll") \
    for (int n = 0; n < NF; ++n) { \
        int e_ = (wc * WCW + n * 16 + lr) * 32 + lg * 8; \
        e_ ^= ((e_ >> 8) & 1) << 4; \
        bf[n] = *(const bf16x8*)&lds[(b_) * BUFE + AELT + (ks_) * (BN * 32) + e_]; \
    } \
} while (0)

#define READAF(b_, ks_, mq_) do { \
    _Pragma("unroll") \
    for (int m = 0; m < 4; ++m) { \
        int e_ = (wr * 128 + ((mq_) * 4 + m) * 16 + lr) * 32 + lg * 8; \
        e_ ^= ((e_ >> 8) & 1) << 4; \
        af[m] = *(const bf16x8*)&lds[(b_) * BUFE + (ks_) * 8192 + e_]; \
    } \
} while (0)

#define DOMFMA(mq_) do { \
    __builtin_amdgcn_s_setprio(1); \
    _Pragma("unroll") \
    for (int m = 0; m < 4; ++m) \
    _Pragma("unroll") \
    for (int n = 0; n < NF; ++n) \
        acc[(mq_) * 4 + m][n] = __builtin_amdgcn_mfma_f32_16x16x32_bf16( \
            bf[n], af[m], acc[(mq_) * 4 + m][n], 0, 0, 0); \
    __builtin_amdgcn_s_setprio(0); \
} while (0)

    f32x4 acc[8][NF];
#pragma unroll
    for (int m = 0; m < 8; ++m)
#pragma unroll
        for (int n = 0; n < NF; ++n) acc[m][n] = (f32x4){0.f, 0.f, 0.f, 0.f};
    bf16x8 af[4], bf[NF];

    stageA(0, 0, 0); stageB(0, 0, 0); stageA(0, 0, 1); stageB(0, 0, 1);
    stageA(1, 1, 0); stageB(1, 1, 0);
    WAIT_VMB();
    BARRIER();

    for (int t = 0; t < NT; ++t) {
        const int cb = t & 1, nb = cb ^ 1;
        const int tp1 = (t + 1 < NT) ? t + 1 : NT - 1;
        const int tp2 = (t + 2 < NT) ? t + 2 : NT - 1;
        READBF(cb, 0); READAF(cb, 0, 0); stageA(tp1, nb, 1);
        BARRIER(); WAIT_LGKM0(); DOMFMA(0); BARRIER();
        READAF(cb, 0, 1); stageB(tp1, nb, 1);
        BARRIER(); WAIT_LGKM0(); DOMFMA(1); BARRIER();
        READBF(cb, 1); READAF(cb, 1, 0); stageA(tp2, cb, 0);
        BARRIER(); WAIT_LGKM0(); DOMFMA(0); BARRIER();
        READAF(cb, 1, 1); stageB(tp2, cb, 0);
        BARRIER(); WAIT_LGKM0(); DOMFMA(1);
        WAIT_VMB();
        BARRIER();
    }

#pragma unroll
    for (int m = 0; m < 8; ++m) {
        int rloc = wr * 128 + m * 16 + lr;
        if (MODE >= 2 && rloc >= rowsValid) continue;
        size_t grow = (size_t)(rowBase + rloc);
        if constexpr (MODE == 2) {
#pragma unroll
            for (int n = 0; n < 2; ++n) {
                int col = (colBase >> 1) + wc * 32 + n * 16 + lg * 4;
                f32x4 v1 = acc[m][n], v3 = acc[m][n + 2];
                ushort4 u;
                u.x = f2bf(silu_f(v1[0]) * v3[0]);
                u.y = f2bf(silu_f(v1[1]) * v3[1]);
                u.z = f2bf(silu_f(v1[2]) * v3[2]);
                u.w = f2bf(silu_f(v1[3]) * v3[3]);
                *(ushort4*)(outB + grow * N + col) = u;
            }
        } else {
#pragma unroll
            for (int n = 0; n < NF; ++n) {
                int col = colBase + wc * WCW + n * 16 + lg * 4;
                f32x4 v = acc[m][n];
                f32x4 bb = *(const f32x4*)(bias + col);
                ushort4 u;
                u.x = f2bf(gelu_f(v[0] + bb[0]));
                u.y = f2bf(gelu_f(v[1] + bb[1]));
                u.z = f2bf(gelu_f(v[2] + bb[2]));
                u.w = f2bf(gelu_f(v[3] + bb[3]));
                *(ushort4*)(outB + grow * N + col) = u;
            }
        }
    }
#undef WAIT_VMB
#undef READBF
#undef READAF
#undef DOMFMA
}

// ---------------------------------------------------------------------------
// Down-GEMM, split into two K=4096 halves as separate blocks (one launch):
//   dense half: yA[r] = hd[r]@W2          (bf16, linear, sorted order)
//   moe   half: y[rev[r]] = 0.5*(hg[r]@ew2[e])   (fp32, scattered, exact cover)
// R6's proven m97 128x128 BK=32 2-phase body. 1024 active blocks = 4/CU.
// 1-D grid 2560: c=wg&7 (XCD), s=wg>>3, x=s&7 (col inner -> A-panel L2 reuse),
// p=c+8*(s>>3) in [0,320): p<64 dense panel, else moe panel (p-64).
// ---------------------------------------------------------------------------
__global__ void __launch_bounds__(256) gemm97sp(
    const u16* __restrict__ Ad, const u16* __restrict__ Ag,
    const u16* __restrict__ W2t, const u16* __restrict__ ew2t,
    u16* __restrict__ yA, float* __restrict__ y,
    const int* __restrict__ offsets, const int* __restrict__ rev) {
    __shared__ u16 ldsA[128 * 32];
    __shared__ u16 ldsB[128 * 32];
    int tid = threadIdx.x, w = tid >> 6, l = tid & 63;
    int wr = w >> 1, wc = w & 1;

    int wg = blockIdx.x;
    int c = wg & 7;
    int s = wg >> 3;
    int x = s & 7;
    int p = c + ((s >> 3) << 3);        // [0,320)

    const u16* Ap;
    const u16* Bp;
    int rowBase, rowsValid = 128;
    bool dense = (p < 64);
    if (dense) {
        rowBase = p * 128;
        Ap = Ad; Bp = W2t;
    } else {
        int pm = p - 64;                 // [0,256): 64 panel slots per expert
        int e = pm >> 6, yl = pm & 63;
        int off = offsets[e], cnt = offsets[e + 1] - off;
        if (yl * 128 >= cnt) return;
        rowBase = off + yl * 128;
        rowsValid = cnt - yl * 128;
        if (rowsValid > 128) rowsValid = 128;
        Ap = Ag; Bp = ew2t + (size_t)e * DD * DI;
    }
    int colBase = x * 128;

    f32x4 acc[4][4];
#pragma unroll
    for (int m = 0; m < 4; ++m)
#pragma unroll
        for (int n = 0; n < 4; ++n) acc[m][n] = (f32x4){0.f, 0.f, 0.f, 0.f};

    int lr = l & 15, lg = l >> 4;
    int ar = l >> 2, ac = (l & 3) * 8;

#pragma unroll 1
    for (int kt = 0; kt < DI / 32; ++kt) {
        int k0 = kt << 5;
        const u16* ga = Ap + (size_t)(rowBase + w * 32 + ar) * DI + k0 + ac;
        gload_lds16(ga, &ldsA[(w * 32) * 32]);
        gload_lds16(ga + (size_t)16 * DI, &ldsA[(w * 32 + 16) * 32]);
        const u16* gb = Bp + (size_t)(colBase + w * 32 + ar) * DI + k0 + ac;
        gload_lds16(gb, &ldsB[(w * 32) * 32]);
        gload_lds16(gb + (size_t)16 * DI, &ldsB[(w * 32 + 16) * 32]);
        __syncthreads();
        bf16x8 af[4], bfr[4];
#pragma unroll
        for (int m = 0; m < 4; ++m)
            af[m] = *(const bf16x8*)&ldsA[(wr * 64 + m * 16 + lr) * 32 + lg * 8];
#pragma unroll
        for (int n = 0; n < 4; ++n)
            bfr[n] = *(const bf16x8*)&ldsB[(wc * 64 + n * 16 + lr) * 32 + lg * 8];
#pragma unroll
        for (int m = 0; m < 4; ++m)
#pragma unroll
            for (int n = 0; n < 4; ++n)
                acc[m][n] = __builtin_amdgcn_mfma_f32_16x16x32_bf16(
                    bfr[n], af[m], acc[m][n], 0, 0, 0);
        __syncthreads();
    }

#pragma unroll
    for (int m = 0; m < 4; ++m) {
        int rloc = wr * 64 + m * 16 + lr;
        if (rloc >= rowsValid) continue;
        int r = rowBase + rloc;
#pragma unroll
        for (int n = 0; n < 4; ++n) {
            int col = colBase + wc * 64 + n * 16 + lg * 4;
            f32x4 v = acc[m][n];
            if (dense) {
                ushort4 u;
                u.x = f2bf(v[0]); u.y = f2bf(v[1]);
                u.z = f2bf(v[2]); u.w = f2bf(v[3]);
                *(ushort4*)(yA + (size_t)r * DD + col) = u;
            } else {
                int tok = rev[r];
                f32x4 rr;
#pragma unroll
                for (int j = 0; j < 4; ++j) rr[j] = 0.5f * v[j];
                *(f32x4*)(y + (size_t)tok * DD + col) = rr;
            }
        }
    }
}

// ---------------------------------------------------------------------------
// Combine: y[rev[r]] += 0.5*(yA[r] + b2).  Wave per sorted row; streaming.
// ---------------------------------------------------------------------------
__global__ void __launch_bounds__(256) combine_kernel(
    const u16* __restrict__ yA, const float* __restrict__ b2,
    const int* __restrict__ rev, float* __restrict__ y) {
    int w = threadIdx.x >> 6, l = threadIdx.x & 63;
    int r = blockIdx.x * 4 + w;
    int tok = rev[r];
    const u16* ar = yA + (size_t)r * DD;
    float* yr = y + (size_t)tok * DD;
#pragma unroll
    for (int i = 0; i < 4; ++i) {
        int c = i * 256 + l * 4;
        ushort4 ua = *(const ushort4*)(ar + c);
        float4 bb = *(const float4*)(b2 + c);
        f32x4 o = *(f32x4*)(yr + c);
        o[0] += 0.5f * (bf2f(ua.x) + bb.x);
        o[1] += 0.5f * (bf2f(ua.y) + bb.y);
        o[2] += 0.5f * (bf2f(ua.z) + bb.z);
        o[3] += 0.5f * (bf2f(ua.w) + bb.w);
        *(f32x4*)(yr + c) = o;
    }
}

// ---------------------------------------------------------------------------
extern "C" void kernel_launch(void* const* d_in, const int* in_sizes, int n_in,
                              void* d_out, int out_size, void* d_ws, size_t ws_size,
                              hipStream_t stream) {
    const float* x   = (const float*)d_in[0];
    const float* W1  = (const float*)d_in[1];
    const float* b1  = (const float*)d_in[2];
    const float* W2  = (const float*)d_in[3];
    const float* b2  = (const float*)d_in[4];
    const float* Wg  = (const float*)d_in[5];
    const float* ew1 = (const float*)d_in[6];
    const float* ew3 = (const float*)d_in[7];
    const float* ew2 = (const float*)d_in[8];
    float* y = (float*)d_out;
    float* auxOut = y + (size_t)MT * DD;

    char* ws = (char*)d_ws;
    size_t off = 0;
    auto take = [&](size_t b) -> void* {
        void* p = ws + off;
        off += (b + 255) & ~(size_t)255;
        return p;
    };
    u16* W1t   = (u16*)take((size_t)DI * DD * 2);           //  8.4 MB
    u16* W2t   = (u16*)take((size_t)DI * DD * 2);           //  8.4 MB
    u16* ew2t  = (u16*)take((size_t)4 * DI * DD * 2);       // 33.6 MB
    u16* xg    = (u16*)take((size_t)(MT + 256) * DD * 2);   // 17.3 MB (+ragged pad)
    u16* hg    = (u16*)take((size_t)(MT + 256) * DI * 2);   // 69.2 MB (moe h)
    int* expertA  = (int*)take(MT * 4);
    int* dstArr   = (int*)take(MT * 4);
    int* revA     = (int*)take(MT * 4);
    float* psum_blk = (float*)take(2048 * 4 * 4);
    int* offsets  = (int*)take(64);
    // Shared region 1: ew13t (67.1 MB, dead after moe-up) aliases hd (69.2 MB,
    // written by dense-up which runs AFTER moe-up).
    size_t ew13Bytes = (size_t)4 * 2 * DI * DD * 2;
    size_t hdBytes   = (size_t)(MT + 256) * DI * 2;
    u16* ew13t = (u16*)take(ew13Bytes > hdBytes ? ew13Bytes : hdBytes);
    u16* hd    = ew13t;
    // Shared region 2: yA (16.8 MB bf16 dense partial) aliases xg (17.3 MB,
    // dead after both ups; down kernel writes it AFTER dense-up completes).
    u16* yA = xg;
    // total ~206 MB

    if (ws_size < off) return;  // insufficient workspace -> visible failure

    dim3 blk(256);
    // weight transpose + bf16 convert (merged: 2 launches)
    transpose_up<<<dim3(DI / 64, DD / 64, 9), blk, 0, stream>>>(W1, ew1, ew3, W1t, ew13t);
    transpose_dn<<<dim3(DD / 64, DI / 64, 5), blk, 0, stream>>>(W2, ew2, W2t, ew2t);
    // routing
    gate_kernel<<<2048, 256, 0, stream>>>(x, Wg, psum_blk, expertA);
    build_lists<<<1, 1024, 0, stream>>>(expertA, psum_blk, dstArr, revA, offsets, auxOut);
    gather_kernel<<<2048, 256, 0, stream>>>(x, dstArr, xg);
    // moe-up FIRST (consumes ew13t), then dense-up (overwrites it with hd)
    gemm8<2, 4><<<dim3(2 * DI / 256, MT / 256, 4), dim3(512), 0, stream>>>(
        xg, ew13t, nullptr, hg, nullptr, offsets, nullptr, DI, DD);
    gemm8<0, 4><<<dim3(DI / 256, MT / 256), dim3(512), 0, stream>>>(
        xg, W1t, b1, hd, nullptr, nullptr, nullptr, DI, DD);
    // down: both K=4096 halves as separate blocks (4 blocks/CU), then combine
    gemm97sp<<<dim3(2560), blk, 0, stream>>>(
        hd, hg, W2t, ew2t, yA, y, offsets, revA);
    combine_kernel<<<2048, blk, 0, stream>>>(yA, b2, revA, y);
}

// Round 12
// 569.693 us; speedup vs baseline: 1.1891x; 1.1891x over previous
//
#include <hip/hip_runtime.h>
#include <hip/hip_bf16.h>

// ---------------------------------------------------------------------------
// HybridFFN: y = 0.5*gelu_mlp(x) + 0.5*top1_moe_swiglu(x), aux load-balance loss
// Ups (K=1024): 256x256 8-phase (T2+T3/T4+T5).
// Down: single fused K=8192 GEMM  y[rev[r]] = 0.5*(hd@W2 + b2 + hg@ew2[e])
//       128x128 BK=32, T3-MINIMUM 2-phase: dbuf LDS, stage(t+1) issued BEFORE
//       compute(t), ONE __syncthreads per K-step. XCD-locality decode.
// Memory plan (~206 MB): hd ALIASES ew13t (dead after moe-up).
// ---------------------------------------------------------------------------

static constexpr int MT = 8192;   // B*S tokens
static constexpr int DD = 1024;   // model dim
static constexpr int DI = 4096;   // inner dim

typedef float f32x4 __attribute__((ext_vector_type(4)));
typedef __bf16 bf16x8 __attribute__((ext_vector_type(8)));
typedef unsigned short u16;

__device__ __forceinline__ u16 f2bf(float f) {
    union { __hip_bfloat16 b; u16 u; } v;
    v.b = __float2bfloat16(f);
    return v.u;
}

__device__ __forceinline__ void gload_lds16(const void* g, void* l) {
    __builtin_amdgcn_global_load_lds(
        (const __attribute__((address_space(1))) void*)g,
        (__attribute__((address_space(3))) void*)l, 16, 0, 0);
}

__device__ __forceinline__ float gelu_f(float v) {
    return 0.5f * v * (1.0f + erff(v * 0.70710678118654752f));
}
__device__ __forceinline__ float silu_f(float v) {
    return v / (1.0f + expf(-v));
}

#define FENCE() asm volatile("" ::: "memory")
#define BARRIER() do { FENCE(); __builtin_amdgcn_s_barrier(); FENCE(); } while (0)
#define WAIT_LGKM0() asm volatile("s_waitcnt lgkmcnt(0)" ::: "memory")

// ---------------------------------------------------------------------------
// Transpose tile helper: src f32 [K][N] -> dst bf16 [N'][K], 64x64 tile.
// pack=1 remaps dst row n -> (n/32)*64 + (n%32) + packOff  (SwiGLU col-pairing)
// ---------------------------------------------------------------------------
__device__ __forceinline__ void transpose_tile(
    const float* __restrict__ s, u16* __restrict__ d, int K, int N,
    int pack, int packOff) {
    __shared__ u16 t[64][72];
    int n0 = blockIdx.x * 64, k0 = blockIdx.y * 64;
    int tid = threadIdx.x;
    int c = tid & 15;
    int r = tid >> 4;
#pragma unroll
    for (int p = 0; p < 4; ++p) {
        int k = r + p * 16;
        float4 v = *(const float4*)(s + (size_t)(k0 + k) * N + n0 + c * 4);
        t[c * 4 + 0][k] = f2bf(v.x);
        t[c * 4 + 1][k] = f2bf(v.y);
        t[c * 4 + 2][k] = f2bf(v.z);
        t[c * 4 + 3][k] = f2bf(v.w);
    }
    __syncthreads();
    int n = tid >> 2, kc = (tid & 3) * 16;
    const uint4* p0 = (const uint4*)&t[n][kc];
    uint4 a = p0[0], b = p0[1];
    int gn = n0 + n;
    int dr = pack ? ((gn >> 5) * 64 + (gn & 31) + packOff) : gn;
    uint4* o = (uint4*)(d + (size_t)dr * K + k0 + kc);
    o[0] = a; o[1] = b;
}

// up-weights: z=0 -> W1->W1t; z in 1..4 -> ew1[z-1]->ew13t(packOff 0);
//             z in 5..8 -> ew3[z-5]->ew13t(packOff 32).   [K=DD, N=DI]
__global__ void __launch_bounds__(256) transpose_up(
    const float* __restrict__ W1, const float* __restrict__ ew1,
    const float* __restrict__ ew3, u16* __restrict__ W1t,
    u16* __restrict__ ew13t) {
    int z = blockIdx.z;
    if (z == 0) {
        transpose_tile(W1, W1t, DD, DI, 0, 0);
    } else if (z <= 4) {
        transpose_tile(ew1 + (size_t)(z - 1) * DD * DI,
                       ew13t + (size_t)(z - 1) * 2 * DD * DI, DD, DI, 1, 0);
    } else {
        transpose_tile(ew3 + (size_t)(z - 5) * DD * DI,
                       ew13t + (size_t)(z - 5) * 2 * DD * DI, DD, DI, 1, 32);
    }
}

// down-weights: z=0 -> W2->W2t; z in 1..4 -> ew2[z-1]->ew2t.   [K=DI, N=DD]
__global__ void __launch_bounds__(256) transpose_dn(
    const float* __restrict__ W2, const float* __restrict__ ew2,
    u16* __restrict__ W2t, u16* __restrict__ ew2t) {
    int z = blockIdx.z;
    if (z == 0) {
        transpose_tile(W2, W2t, DI, DD, 0, 0);
    } else {
        transpose_tile(ew2 + (size_t)(z - 1) * DI * DD,
                       ew2t + (size_t)(z - 1) * DI * DD, DI, DD, 0, 0);
    }
}

// ---------------------------------------------------------------------------
// Gating: one wave per token; fp64 logits, softmax, argmax. No atomics.
// ---------------------------------------------------------------------------
__global__ void __launch_bounds__(256) gate_kernel(
    const float* __restrict__ x, const float* __restrict__ Wg,
    float* __restrict__ psum_blk, int* __restrict__ expertA) {
    int w = threadIdx.x >> 6, l = threadIdx.x & 63;
    int t = blockIdx.x * 4 + w;
    const float* xr = x + (size_t)t * DD;
    double a0 = 0, a1 = 0, a2 = 0, a3 = 0;
#pragma unroll
    for (int i = 0; i < 4; ++i) {
        int k = i * 256 + l * 4;
        float4 xv = *(const float4*)(xr + k);
        float4 w0 = *(const float4*)(Wg + (size_t)(k + 0) * 4);
        float4 w1 = *(const float4*)(Wg + (size_t)(k + 1) * 4);
        float4 w2 = *(const float4*)(Wg + (size_t)(k + 2) * 4);
        float4 w3 = *(const float4*)(Wg + (size_t)(k + 3) * 4);
        a0 += (double)xv.x * w0.x + (double)xv.y * w1.x + (double)xv.z * w2.x + (double)xv.w * w3.x;
        a1 += (double)xv.x * w0.y + (double)xv.y * w1.y + (double)xv.z * w2.y + (double)xv.w * w3.y;
        a2 += (double)xv.x * w0.z + (double)xv.y * w1.z + (double)xv.z * w2.z + (double)xv.w * w3.z;
        a3 += (double)xv.x * w0.w + (double)xv.y * w1.w + (double)xv.z * w2.w + (double)xv.w * w3.w;
    }
#pragma unroll
    for (int o = 32; o; o >>= 1) {
        a0 += __shfl_down(a0, o); a1 += __shfl_down(a1, o);
        a2 += __shfl_down(a2, o); a3 += __shfl_down(a3, o);
    }
    __shared__ float wps[4][4];
    if (l == 0) {
        double lg[4] = {a0, a1, a2, a3};
        int best = 0;
#pragma unroll
        for (int e = 1; e < 4; ++e) if (lg[e] > lg[best]) best = e;
        double m = lg[best], s = 0, p[4];
#pragma unroll
        for (int e = 0; e < 4; ++e) { p[e] = exp(lg[e] - m); s += p[e]; }
#pragma unroll
        for (int e = 0; e < 4; ++e) wps[w][e] = (float)(p[e] / s);
        expertA[t] = best;
    }
    __syncthreads();
    if (threadIdx.x < 4)
        psum_blk[blockIdx.x * 4 + threadIdx.x] =
            wps[0][threadIdx.x] + wps[1][threadIdx.x] + wps[2][threadIdx.x] + wps[3][threadIdx.x];
}

// ---------------------------------------------------------------------------
// Single-block stable compaction + offsets + aux loss.
// ---------------------------------------------------------------------------
__global__ void __launch_bounds__(1024) build_lists(
    const int* __restrict__ expertA, const float* __restrict__ psum_blk,
    int* __restrict__ dstArr, int* __restrict__ rev,
    int* __restrict__ offsets, float* __restrict__ auxOut) {
    __shared__ int sc[4][1024];
    __shared__ float fs[1024];
    __shared__ float psum_s[4];
    __shared__ int tot_s[4], off_s[4];
    int tid = threadIdx.x;
    int le[8]; int c[4] = {0, 0, 0, 0};
#pragma unroll
    for (int i = 0; i < 8; ++i) { int e = expertA[tid * 8 + i]; le[i] = e; c[e]++; }
#pragma unroll
    for (int e = 0; e < 4; ++e) sc[e][tid] = c[e];
    __syncthreads();
    for (int o = 1; o < 1024; o <<= 1) {
        int v[4];
#pragma unroll
        for (int e = 0; e < 4; ++e) v[e] = (tid >= o) ? sc[e][tid - o] : 0;
        __syncthreads();
#pragma unroll
        for (int e = 0; e < 4; ++e) if (tid >= o) sc[e][tid] += v[e];
        __syncthreads();
    }
    if (tid == 0) {
        int o = 0;
#pragma unroll
        for (int e = 0; e < 4; ++e) {
            tot_s[e] = sc[e][1023]; off_s[e] = o; offsets[e] = o; o += tot_s[e];
        }
        offsets[4] = o;
    }
    __syncthreads();
    int base[4];
#pragma unroll
    for (int e = 0; e < 4; ++e) base[e] = off_s[e] + sc[e][tid] - c[e];
#pragma unroll
    for (int i = 0; i < 8; ++i) {
        int e = le[i]; int d = base[e]++; int t = tid * 8 + i;
        dstArr[t] = d; rev[d] = t;
    }
    float ps[4];
#pragma unroll
    for (int e = 0; e < 4; ++e)
        ps[e] = psum_blk[(2 * tid) * 4 + e] + psum_blk[(2 * tid + 1) * 4 + e];
    for (int e = 0; e < 4; ++e) {
        fs[tid] = ps[e]; __syncthreads();
        for (int o = 512; o; o >>= 1) { if (tid < o) fs[tid] += fs[tid + o]; __syncthreads(); }
        if (tid == 0) psum_s[e] = fs[0];
        __syncthreads();
    }
    if (tid == 0) {
        float a = 0;
#pragma unroll
        for (int e = 0; e < 4; ++e)
            a += ((float)tot_s[e] * (1.f / 8192.f)) * (psum_s[e] * (1.f / 8192.f));
        auxOut[0] = 4.f * a;
    }
}

// ---------------------------------------------------------------------------
// Gather: bf16 rows into xg (expert-sorted order only).
// ---------------------------------------------------------------------------
__global__ void __launch_bounds__(256) gather_kernel(
    const float* __restrict__ x, const int* __restrict__ dstArr,
    u16* __restrict__ xg) {
    int w = threadIdx.x >> 6, l = threadIdx.x & 63;
    int t = blockIdx.x * 4 + w;
    int dst = dstArr[t];
    const float* xr = x + (size_t)t * DD;
#pragma unroll
    for (int i = 0; i < 4; ++i) {
        int k = i * 256 + l * 4;
        float4 v = *(const float4*)(xr + k);
        ushort4 u;
        u.x = f2bf(v.x); u.y = f2bf(v.y); u.z = f2bf(v.z); u.w = f2bf(v.w);
        *(ushort4*)(xg + (size_t)dst * DD + k) = u;
    }
}

// ---------------------------------------------------------------------------
// Up-GEMMs: 256-row 8-phase MFMA GEMM (BM=256, BK=64, 8 waves 2x4, dbuf LDS,
// st_16x32 swizzle, counted vmcnt, setprio).
// MODE 0 (NF=4): h = gelu(A@W + b)            -> bf16 (rows = sorted tokens)
// MODE 2 (NF=4): h = silu(A@W1)*(A@W3)        -> bf16, ragged, packed B cols
// ---------------------------------------------------------------------------
template <int MODE, int NF>
__global__ void __launch_bounds__(512, 2) gemm8(
    const u16* __restrict__ A, const u16* __restrict__ Bw,
    const float* __restrict__ bias,
    u16* __restrict__ outB, float* __restrict__ outF,
    const int* __restrict__ offsets, const int* __restrict__ rev,
    int N, int K) {
    constexpr int BN   = NF * 64;
    constexpr int WCW  = NF * 16;
    constexpr int AELT = 2 * 256 * 32;
    constexpr int BUFE = AELT + 2 * BN * 32;
    constexpr int NIB  = NF / 2;
    __shared__ u16 lds[2 * BUFE];

    const int tid = threadIdx.x;
    const int w = tid >> 6, l = tid & 63;
    const int lr = l & 15, lg = l >> 4;
    const int wr = w >> 2, wc = w & 3;

    int rowBase, rowsValid = 256;
    const u16* Bp = Bw;
    if constexpr (MODE >= 2) {
        int e = blockIdx.z;
        int off = offsets[e], cnt = offsets[e + 1] - off;
        if ((int)blockIdx.y * 256 >= cnt) return;
        rowBase = off + blockIdx.y * 256;
        rowsValid = cnt - (int)blockIdx.y * 256;
        if (rowsValid > 256) rowsValid = 256;
        Bp = Bw + (size_t)e * ((size_t)2 * DD * DI);
    } else {
        rowBase = blockIdx.y * 256;
    }
    const int colBase = blockIdx.x * BN;
    const int NT = K >> 6;

    auto stageA = [&](int kt, int b, int ks) {
        const int kk = (kt << 6) + (ks << 5);
#pragma unroll
        for (int i = 0; i < 2; ++i) {
            int o = ((w << 1) + i) * 512 + (l << 3);
            int o2 = o ^ (((o >> 8) & 1) << 4);
            gload_lds16(A + (size_t)(rowBase + (o2 >> 5)) * K + kk + (o2 & 31),
                        &lds[b * BUFE + ks * 8192 + ((w << 1) + i) * 512]);
        }
    };
    auto stageB = [&](int kt, int b, int ks) {
        const int kk = (kt << 6) + (ks << 5);
#pragma unroll
        for (int i = 0; i < NIB; ++i) {
            int o = (w * NIB + i) * 512 + (l << 3);
            int o2 = o ^ (((o >> 8) & 1) << 4);
            gload_lds16(Bp + (size_t)(colBase + (o2 >> 5)) * K + kk + (o2 & 31),
                        &lds[b * BUFE + AELT + ks * (BN * 32) + (w * NIB + i) * 512]);
        }
    };

#define WAIT_VMB() do { \
    if constexpr (NF == 4) asm volatile("s_waitcnt vmcnt(4)" ::: "memory"); \
    else                   asm volatile("s_waitcnt vmcnt(3)" ::: "memory"); \
} while (0)

#define READBF(b_, ks_) do { \
    _Pragma("unroll") \
    for (int n = 0; n < NF; ++n) { \
        int e_ = (wc * WCW + n * 16 + lr) * 32 + lg * 8; \
        e_ ^= ((e_ >> 8) & 1) << 4; \
        bf[n] = *(const bf16x8*)&lds[(b_) * BUFE + AELT + (ks_) * (BN * 32) + e_]; \
    } \
} while (0)

#define READAF(b_, ks_, mq_) do { \
    _Pragma("unroll") \
    for (int m = 0; m < 4; ++m) { \
        int e_ = (wr * 128 + ((mq_) * 4 + m) * 16 + lr) * 32 + lg * 8; \
        e_ ^= ((e_ >> 8) & 1) << 4; \
        af[m] = *(const bf16x8*)&lds[(b_) * BUFE + (ks_) * 8192 + e_]; \
    } \
} while (0)

#define DOMFMA(mq_) do { \
    __builtin_amdgcn_s_setprio(1); \
    _Pragma("unroll") \
    for (int m = 0; m < 4; ++m) \
    _Pragma("unroll") \
    for (int n = 0; n < NF; ++n) \
        acc[(mq_) * 4 + m][n] = __builtin_amdgcn_mfma_f32_16x16x32_bf16( \
            bf[n], af[m], acc[(mq_) * 4 + m][n], 0, 0, 0); \
    __builtin_amdgcn_s_setprio(0); \
} while (0)

    f32x4 acc[8][NF];
#pragma unroll
    for (int m = 0; m < 8; ++m)
#pragma unroll
        for (int n = 0; n < NF; ++n) acc[m][n] = (f32x4){0.f, 0.f, 0.f, 0.f};
    bf16x8 af[4], bf[NF];

    stageA(0, 0, 0); stageB(0, 0, 0); stageA(0, 0, 1); stageB(0, 0, 1);
    stageA(1, 1, 0); stageB(1, 1, 0);
    WAIT_VMB();
    BARRIER();

    for (int t = 0; t < NT; ++t) {
        const int cb = t & 1, nb = cb ^ 1;
        const int tp1 = (t + 1 < NT) ? t + 1 : NT - 1;
        const int tp2 = (t + 2 < NT) ? t + 2 : NT - 1;
        READBF(cb, 0); READAF(cb, 0, 0); stageA(tp1, nb, 1);
        BARRIER(); WAIT_LGKM0(); DOMFMA(0); BARRIER();
        READAF(cb, 0, 1); stageB(tp1, nb, 1);
        BARRIER(); WAIT_LGKM0(); DOMFMA(1); BARRIER();
        READBF(cb, 1); READAF(cb, 1, 0); stageA(tp2, cb, 0);
        BARRIER(); WAIT_LGKM0(); DOMFMA(0); BARRIER();
        READAF(cb, 1, 1); stageB(tp2, cb, 0);
        BARRIER(); WAIT_LGKM0(); DOMFMA(1);
        WAIT_VMB();
        BARRIER();
    }

#pragma unroll
    for (int m = 0; m < 8; ++m) {
        int rloc = wr * 128 + m * 16 + lr;
        if (MODE >= 2 && rloc >= rowsValid) continue;
        size_t grow = (size_t)(rowBase + rloc);
        if constexpr (MODE == 2) {
#pragma unroll
            for (int n = 0; n < 2; ++n) {
                int col = (colBase >> 1) + wc * 32 + n * 16 + lg * 4;
                f32x4 v1 = acc[m][n], v3 = acc[m][n + 2];
                ushort4 u;
                u.x = f2bf(silu_f(v1[0]) * v3[0]);
                u.y = f2bf(silu_f(v1[1]) * v3[1]);
                u.z = f2bf(silu_f(v1[2]) * v3[2]);
                u.w = f2bf(silu_f(v1[3]) * v3[3]);
                *(ushort4*)(outB + grow * N + col) = u;
            }
        } else {
#pragma unroll
            for (int n = 0; n < NF; ++n) {
                int col = colBase + wc * WCW + n * 16 + lg * 4;
                f32x4 v = acc[m][n];
                f32x4 bb = *(const f32x4*)(bias + col);
                ushort4 u;
                u.x = f2bf(gelu_f(v[0] + bb[0]));
                u.y = f2bf(gelu_f(v[1] + bb[1]));
                u.z = f2bf(gelu_f(v[2] + bb[2]));
                u.w = f2bf(gelu_f(v[3] + bb[3]));
                *(ushort4*)(outB + grow * N + col) = u;
            }
        }
    }
#undef WAIT_VMB
#undef READBF
#undef READAF
#undef DOMFMA
}

// ---------------------------------------------------------------------------
// Fused down-GEMM: 128x128 BK=32, K=8192 concat, T3-MINIMUM 2-phase:
//   y[rev[r]] = 0.5*( hd[r]@W2 + b2 + hg[r]@ew2[e] )
// Per K-step: stage(t+1 -> other buf) issued FIRST, then ds_read+MFMA of
// current buf, then ONE __syncthreads (drains vmcnt+lgkmcnt, publishes).
// Stage overlaps compute; half the barriers of the R6 body.
// XCD-locality decode: 8 col-blocks of one A-panel at stride-8 wg (same XCD).
// ---------------------------------------------------------------------------
__global__ void __launch_bounds__(256) gemm97cat(
    const u16* __restrict__ Ad, const u16* __restrict__ Ag,
    const u16* __restrict__ W2t, const u16* __restrict__ ew2t,
    const float* __restrict__ b2, float* __restrict__ y,
    const int* __restrict__ offsets, const int* __restrict__ rev) {
    __shared__ u16 ldsA[2][128 * 32];
    __shared__ u16 ldsB[2][128 * 32];
    int tid = threadIdx.x, w = tid >> 6, l = tid & 63;
    int wr = w >> 1, wc = w & 1;

    // XCD-locality decode
    int wg = blockIdx.x;
    int c = wg & 7;
    int s = wg >> 3;
    int x = s & 7;                      // column panel (fast within XCD)
    int p = c + ((s >> 3) << 3);        // global row-panel index, [0,256)
    int e = p >> 6;
    int yl = p & 63;

    int off = offsets[e], cnt = offsets[e + 1] - off;
    if (yl * 128 >= cnt) return;
    int rowBase = off + yl * 128;
    int rowsValid = cnt - yl * 128;
    if (rowsValid > 128) rowsValid = 128;
    int colBase = x * 128;

    f32x4 acc[4][4];
#pragma unroll
    for (int m = 0; m < 4; ++m)
#pragma unroll
        for (int n = 0; n < 4; ++n) acc[m][n] = (f32x4){0.f, 0.f, 0.f, 0.f};

    int lr = l & 15, lg = l >> 4;
    int ar = l >> 2, ac = (l & 3) * 8;
    const u16* Bm = ew2t + (size_t)e * DD * DI;
    constexpr int NT = 2 * DI / 32;     // 256 K-steps

    // stage one 128x32 A-tile + B-tile of global k-step kt into buffer b
    auto stage = [&](int kt, int b) {
        int half = kt >> 7;
        int k0 = (kt & 127) << 5;
        const u16* Ap = half ? Ag : Ad;
        const u16* Bp = half ? Bm : W2t;
        const u16* ga = Ap + (size_t)(rowBase + w * 32 + ar) * DI + k0 + ac;
        gload_lds16(ga, &ldsA[b][(w * 32) * 32]);
        gload_lds16(ga + (size_t)16 * DI, &ldsA[b][(w * 32 + 16) * 32]);
        const u16* gb = Bp + (size_t)(colBase + w * 32 + ar) * DI + k0 + ac;
        gload_lds16(gb, &ldsB[b][(w * 32) * 32]);
        gload_lds16(gb + (size_t)16 * DI, &ldsB[b][(w * 32 + 16) * 32]);
    };

    stage(0, 0);
    __syncthreads();

#pragma unroll 1
    for (int kt = 0; kt < NT; ++kt) {
        const int cb = kt & 1;
        if (kt + 1 < NT) stage(kt + 1, cb ^ 1);   // overlaps compute below
        bf16x8 af[4], bfr[4];
#pragma unroll
        for (int m = 0; m < 4; ++m)
            af[m] = *(const bf16x8*)&ldsA[cb][(wr * 64 + m * 16 + lr) * 32 + lg * 8];
#pragma unroll
        for (int n = 0; n < 4; ++n)
            bfr[n] = *(const bf16x8*)&ldsB[cb][(wc * 64 + n * 16 + lr) * 32 + lg * 8];
        __builtin_amdgcn_s_setprio(1);
#pragma unroll
        for (int m = 0; m < 4; ++m)
#pragma unroll
            for (int n = 0; n < 4; ++n)
                acc[m][n] = __builtin_amdgcn_mfma_f32_16x16x32_bf16(
                    bfr[n], af[m], acc[m][n], 0, 0, 0);
        __builtin_amdgcn_s_setprio(0);
        __syncthreads();                           // one barrier per K-step
    }

#pragma unroll
    for (int m = 0; m < 4; ++m) {
        int rloc = wr * 64 + m * 16 + lr;
        if (rloc >= rowsValid) continue;
        int tok = rev[rowBase + rloc];
#pragma unroll
        for (int n = 0; n < 4; ++n) {
            int col = colBase + wc * 64 + n * 16 + lg * 4;
            f32x4 v = acc[m][n];
            f32x4 bb = *(const f32x4*)(b2 + col);
            f32x4 r;
#pragma unroll
            for (int j = 0; j < 4; ++j) r[j] = 0.5f * (v[j] + bb[j]);
            *(f32x4*)(y + (size_t)tok * DD + col) = r;
        }
    }
}

// ---------------------------------------------------------------------------
extern "C" void kernel_launch(void* const* d_in, const int* in_sizes, int n_in,
                              void* d_out, int out_size, void* d_ws, size_t ws_size,
                              hipStream_t stream) {
    const float* x   = (const float*)d_in[0];
    const float* W1  = (const float*)d_in[1];
    const float* b1  = (const float*)d_in[2];
    const float* W2  = (const float*)d_in[3];
    const float* b2  = (const float*)d_in[4];
    const float* Wg  = (const float*)d_in[5];
    const float* ew1 = (const float*)d_in[6];
    const float* ew3 = (const float*)d_in[7];
    const float* ew2 = (const float*)d_in[8];
    float* y = (float*)d_out;
    float* auxOut = y + (size_t)MT * DD;

    char* ws = (char*)d_ws;
    size_t off = 0;
    auto take = [&](size_t b) -> void* {
        void* p = ws + off;
        off += (b + 255) & ~(size_t)255;
        return p;
    };
    u16* W1t   = (u16*)take((size_t)DI * DD * 2);           //  8.4 MB
    u16* W2t   = (u16*)take((size_t)DI * DD * 2);           //  8.4 MB
    u16* ew2t  = (u16*)take((size_t)4 * DI * DD * 2);       // 33.6 MB
    u16* xg    = (u16*)take((size_t)(MT + 256) * DD * 2);   // 17.3 MB (+ragged pad)
    u16* hg    = (u16*)take((size_t)(MT + 256) * DI * 2);   // 69.2 MB (moe h)
    int* expertA  = (int*)take(MT * 4);
    int* dstArr   = (int*)take(MT * 4);
    int* revA     = (int*)take(MT * 4);
    float* psum_blk = (float*)take(2048 * 4 * 4);
    int* offsets  = (int*)take(64);
    // Shared region: ew13t (67.1 MB, dead after moe-up) aliases hd (69.2 MB,
    // written by dense-up which runs AFTER moe-up).
    size_t ew13Bytes = (size_t)4 * 2 * DI * DD * 2;
    size_t hdBytes   = (size_t)(MT + 256) * DI * 2;
    u16* ew13t = (u16*)take(ew13Bytes > hdBytes ? ew13Bytes : hdBytes);
    u16* hd    = ew13t;
    // total ~206 MB

    if (ws_size < off) return;  // insufficient workspace -> visible failure

    dim3 blk(256);
    // weight transpose + bf16 convert (merged: 2 launches)
    transpose_up<<<dim3(DI / 64, DD / 64, 9), blk, 0, stream>>>(W1, ew1, ew3, W1t, ew13t);
    transpose_dn<<<dim3(DD / 64, DI / 64, 5), blk, 0, stream>>>(W2, ew2, W2t, ew2t);
    // routing
    gate_kernel<<<2048, 256, 0, stream>>>(x, Wg, psum_blk, expertA);
    build_lists<<<1, 1024, 0, stream>>>(expertA, psum_blk, dstArr, revA, offsets, auxOut);
    gather_kernel<<<2048, 256, 0, stream>>>(x, dstArr, xg);
    // moe-up FIRST (consumes ew13t), then dense-up (overwrites it with hd)
    gemm8<2, 4><<<dim3(2 * DI / 256, MT / 256, 4), dim3(512), 0, stream>>>(
        xg, ew13t, nullptr, hg, nullptr, offsets, nullptr, DI, DD);
    gemm8<0, 4><<<dim3(DI / 256, MT / 256), dim3(512), 0, stream>>>(
        xg, W1t, b1, hd, nullptr, nullptr, nullptr, DI, DD);
    // fused down: one pass over y, no RMW, T3-minimum dbuf, XCD 1-D grid
    gemm97cat<<<dim3(2048), blk, 0, stream>>>(
        hd, hg, W2t, ew2t, b2, y, offsets, revA);
}